// Round 11
// baseline (85.967 us; speedup 1.0000x reference)
//
#include <hip/hip_runtime.h>
#include <math.h>

#define CCH   192
#define RCH   48
#define NB    16
#define HW    9216    // 96*96
#define BCTOT (NB*CCH) // 3072

// ---------------------------------------------------------------------------
// Kernel 1: persistent-wave stats. 3456 waves; each wave owns 8 consecutive
// pooled 32x32 blocks and streams them with a 2-stage register prefetch
// pipeline (loads for block it+1 issued before reducing block it), so the
// CU's read pipeline never drains at block boundaries. No LDS, no barriers.
// ---------------------------------------------------------------------------
__device__ __forceinline__ void reduce_store(float4 v0, float4 v1, float4 v2,
                                             float4 v3, int l, int g,
                                             float* __restrict__ pooled,
                                             float* __restrict__ wmax)
{
    float s = (v0.x + v0.y + v0.z + v0.w) + (v1.x + v1.y + v1.z + v1.w)
            + (v2.x + v2.y + v2.z + v2.w) + (v3.x + v3.y + v3.z + v3.w);
    float m = fmaxf(fmaxf(fmaxf(v0.x, v0.y), fmaxf(v0.z, v0.w)),
             fmaxf(fmaxf(fmaxf(v1.x, v1.y), fmaxf(v1.z, v1.w)),
             fmaxf(fmaxf(fmaxf(v2.x, v2.y), fmaxf(v2.z, v2.w)),
                   fmaxf(fmaxf(v3.x, v3.y), fmaxf(v3.z, v3.w)))));
#pragma unroll
    for (int off = 32; off > 0; off >>= 1) {
        s += __shfl_down(s, off);
        m = fmaxf(m, __shfl_down(m, off));
    }
    if (l == 0) {
        pooled[g] = s * (1.0f / 1024.0f);
        wmax[g]   = m;
    }
}

__global__ __launch_bounds__(256) void k_stats(const float* __restrict__ x,
                                               float* __restrict__ pooled,
                                               float* __restrict__ wmax)
{
    int t = threadIdx.x;
    int wv = blockIdx.x * 4 + (t >> 6);    // wave id 0..3455
    int l = t & 63;
    int lr = l >> 1;                        // row offset within pooled block
    int lc = (l & 1) * 4;                   // f4-col offset within pooled block

    int g0 = wv * 8;                        // first of 8 pooled blocks

    const float4* p;
    {
        int g = g0;
        int bc = g / 9, k = g % 9;
        p = (const float4*)(x + (size_t)bc * HW) + (k / 3 * 32 + lr) * 24 + (k % 3 * 8 + lc);
    }
    float4 a0 = p[0], a1 = p[1], a2 = p[2], a3 = p[3];
    float4 b0, b1, b2, b3;

#pragma unroll
    for (int it = 0; it < 8; it += 2) {
        if (it + 1 < 8) {
            int g = g0 + it + 1;
            int bc = g / 9, k = g % 9;
            const float4* q = (const float4*)(x + (size_t)bc * HW)
                              + (k / 3 * 32 + lr) * 24 + (k % 3 * 8 + lc);
            b0 = q[0]; b1 = q[1]; b2 = q[2]; b3 = q[3];
        }
        reduce_store(a0, a1, a2, a3, l, g0 + it, pooled, wmax);
        if (it + 2 < 8) {
            int g = g0 + it + 2;
            int bc = g / 9, k = g % 9;
            const float4* q = (const float4*)(x + (size_t)bc * HW)
                              + (k / 3 * 32 + lr) * 24 + (k % 3 * 8 + lc);
            a0 = q[0]; a1 = q[1]; a2 = q[2]; a3 = q[3];
        }
        reduce_store(b0, b1, b2, b3, l, g0 + it + 1, pooled, wmax);
    }
}

// ---------------------------------------------------------------------------
// Kernel 2a: per-batch theta + h = relu(bn(proj1(pooled))).
// Finishes avg (= mean of 9 pooled) and mx (= max of 9 wmax) in LDS.
// ---------------------------------------------------------------------------
__global__ __launch_bounds__(256) void k_coeff1(
    const float* __restrict__ pooled, const float* __restrict__ wmax,
    const float* __restrict__ cam_w1, const float* __restrict__ cam_w2,
    const float* __restrict__ proj_w1,
    const float* __restrict__ bn_gamma, const float* __restrict__ bn_beta,
    float* __restrict__ theta, float* __restrict__ hh)
{
    int b = blockIdx.x;
    int t = threadIdx.x;
    __shared__ float s_av[CCH], s_mx[CCH], s_pool[CCH * 9], s_wm[CCH * 9];
    __shared__ float s_h1p[96], s_h1[RCH];
    for (int i = t; i < CCH * 9; i += 256) {
        s_pool[i] = pooled[b * CCH * 9 + i];
        s_wm[i]   = wmax[b * CCH * 9 + i];
    }
    __syncthreads();
    if (t < CCH) {
        float sa = 0.f, sm = -INFINITY;
#pragma unroll
        for (int k = 0; k < 9; ++k) {
            sa += s_pool[t * 9 + k];
            sm = fmaxf(sm, s_wm[t * 9 + k]);
        }
        s_av[t] = sa * (1.0f / 9.0f);
        s_mx[t] = sm;
    }
    __syncthreads();
    if (t < 96) {
        int r = t % 48, sel = t / 48;
        const float* src = sel ? s_mx : s_av;
        const float* w = cam_w1 + r * CCH;
        float acc = 0.f;
        for (int c = 0; c < CCH; ++c) acc += src[c] * w[c];
        s_h1p[sel * 48 + r] = fmaxf(acc, 0.f);
    }
    __syncthreads();
    if (t < RCH) s_h1[t] = s_h1p[t] + s_h1p[48 + t];
    __syncthreads();
    if (t < CCH) {
        const float* w = cam_w2 + t * RCH;
        float acc = 0.f;
        for (int r = 0; r < RCH; ++r) acc += s_h1[r] * w[r];
        theta[b * CCH + t] = 1.0f / (1.0f + expf(-acc));
    }
    float bn_s = 1.0f / sqrtf(1.0f + 1e-5f);
    for (int i = t; i < RCH * 9; i += 256) {
        int r = i / 9, k = i % 9;
        const float* w = proj_w1 + r * CCH;
        float acc = 0.f;
        for (int c = 0; c < CCH; ++c) acc += s_pool[c * 9 + k] * w[c];
        float val = acc * (bn_gamma[r] * bn_s) + bn_beta[r];
        hh[b * RCH * 9 + i] = fmaxf(val, 0.f);
    }
}

// ---------------------------------------------------------------------------
// Kernel 2b: per-(b,c,k) softmax over G=4 groups -> conv weight
// ---------------------------------------------------------------------------
__global__ __launch_bounds__(256) void k_coeff2(
    const float* __restrict__ hh, const float* __restrict__ proj_w2,
    const float* __restrict__ adk, float* __restrict__ wgt)
{
    int gid = blockIdx.x * 256 + threadIdx.x;
    if (gid >= BCTOT * 9) return;
    int b = gid / (CCH * 9);
    int rem = gid % (CCH * 9);
    int c = rem / 9, k = rem % 9;
    const float* hv = hh + b * RCH * 9 + k;
    float sg[4];
#pragma unroll
    for (int g = 0; g < 4; ++g) {
        const float* w = proj_w2 + (size_t)(g * CCH + c) * RCH;
        float acc = 0.f;
        for (int r = 0; r < RCH; ++r) acc += hv[r * 9] * w[r];
        sg[g] = acc;
    }
    float mxv = fmaxf(fmaxf(sg[0], sg[1]), fmaxf(sg[2], sg[3]));
    float e[4];
    float sum = 0.f;
#pragma unroll
    for (int g = 0; g < 4; ++g) { e[g] = expf(sg[g] - mxv); sum += e[g]; }
    float inv = 1.0f / sum;
    float acc = 0.f;
#pragma unroll
    for (int g = 0; g < 4; ++g)
        acc += (e[g] * inv) * adk[(size_t)(g * CCH + c) * 9 + k];
    wgt[gid] = acc;
}

// ---------------------------------------------------------------------------
// Kernel 3: depthwise 3x3 conv (pad 1), vertical sliding window (R2-exact).
// Thread: 4-wide x 12-row output strip; walks 14 input rows once,
// 3 rotating accumulators (all indices compile-time via full unroll).
// ---------------------------------------------------------------------------
__global__ __launch_bounds__(256) void k_conv(
    const float* __restrict__ x, const float* __restrict__ wgt,
    const float* __restrict__ theta, float* __restrict__ out)
{
    int gid = blockIdx.x * 256 + threadIdx.x;
    int plane = gid / 192;          // 192 = 8 rowgroups * 24 wq
    int sub   = gid % 192;
    int rg = sub / 24, wq = sub % 24;
    int r0 = rg * 12;
    int w0 = wq * 4;

    float wr[9];
    float wsum = 0.f;
#pragma unroll
    for (int k = 0; k < 9; ++k) { wr[k] = wgt[plane * 9 + k]; wsum += wr[k]; }
    float th = theta[plane];
    wr[4] = wr[4] * (1.f + th) - wsum;   // fold theta-center adjustment

    const float* p = x + (size_t)plane * HW;
    float* o = out + (size_t)plane * HW;

    float acc[3][4];
#pragma unroll
    for (int i = 0; i <= 13; ++i) {
        int r = r0 - 1 + i;
        float win[6];
        bool inr = (r >= 0) && (r < 96);
        const float* prow = p + r * 96;
        if (inr) {
            float4 a = ((const float4*)prow)[wq];
            win[0] = (wq > 0)  ? prow[w0 - 1] : 0.f;
            win[1] = a.x; win[2] = a.y; win[3] = a.z; win[4] = a.w;
            win[5] = (wq < 23) ? prow[w0 + 4] : 0.f;
        } else {
#pragma unroll
            for (int j = 0; j < 6; ++j) win[j] = 0.f;
        }
        if (i <= 11) {
#pragma unroll
            for (int j = 0; j < 4; ++j)
                acc[i % 3][j] = wr[0] * win[j] + wr[1] * win[j + 1] + wr[2] * win[j + 2];
        }
        if (i >= 1 && i <= 12) {
#pragma unroll
            for (int j = 0; j < 4; ++j)
                acc[(i - 1) % 3][j] += wr[3] * win[j] + wr[4] * win[j + 1] + wr[5] * win[j + 2];
        }
        if (i >= 2) {
            const int s = (i - 2) % 3;
#pragma unroll
            for (int j = 0; j < 4; ++j)
                acc[s][j] += wr[6] * win[j] + wr[7] * win[j + 1] + wr[8] * win[j + 2];
            float4 o4;
            o4.x = acc[s][0]; o4.y = acc[s][1]; o4.z = acc[s][2]; o4.w = acc[s][3];
            ((float4*)(o + (size_t)(r - 1) * 96))[wq] = o4;
        }
    }
}

extern "C" void kernel_launch(void* const* d_in, const int* in_sizes, int n_in,
                              void* d_out, int out_size, void* d_ws, size_t ws_size,
                              hipStream_t stream) {
    const float* x        = (const float*)d_in[0];
    const float* cam_w1   = (const float*)d_in[1];
    const float* cam_w2   = (const float*)d_in[2];
    const float* proj_w1  = (const float*)d_in[3];
    const float* bn_gamma = (const float*)d_in[4];
    const float* bn_beta  = (const float*)d_in[5];
    const float* proj_w2  = (const float*)d_in[6];
    const float* adk      = (const float*)d_in[7];
    float* out = (float*)d_out;
    float* ws  = (float*)d_ws;

    float* pooled = ws;            // 27648
    float* wmaxg  = ws + 27648;    // 27648 (aliased: wgt after coeff1 consumes)
    float* theta  = ws + 55296;    // 3072
    float* hh     = ws + 58368;    // 6912
    float* wgt    = wmaxg;         // alias — wmax dead after k_coeff1

    // 864 blocks x 4 waves x 8 pooled-blocks = 27648
    k_stats  <<<864, 256, 0, stream>>>(x, pooled, wmaxg);
    k_coeff1 <<<NB, 256, 0, stream>>>(pooled, wmaxg, cam_w1, cam_w2,
                                      proj_w1, bn_gamma, bn_beta, theta, hh);
    k_coeff2 <<<(BCTOT * 9) / 256, 256, 0, stream>>>(hh, proj_w2, adk, wgt);
    k_conv   <<<(BCTOT * 192) / 256, 256, 0, stream>>>(x, wgt, theta, out);
}

// Round 12
// 84.278 us; speedup vs baseline: 1.0201x; 1.0201x over previous
//
#include <hip/hip_runtime.h>
#include <math.h>

#define CCH   192
#define RCH   48
#define NB    16
#define HW    9216    // 96*96
#define BCTOT (NB*CCH) // 3072

// ---------------------------------------------------------------------------
// Kernel 1: ONE WAVE per pooled 32x32 block (tied-best of 5 variants; at the
// measured ~3.1 TB/s pure-read ceiling). Lane reads 64B contiguous; 12-shfl
// wave reduce; lane 0 writes pooled mean + block max.
// ---------------------------------------------------------------------------
__global__ __launch_bounds__(256) void k_stats(const float* __restrict__ x,
                                               float* __restrict__ pooled,
                                               float* __restrict__ wmax)
{
    int t = threadIdx.x;
    int g = blockIdx.x * 4 + (t >> 6);     // global wave id, 0..27647
    int l = t & 63;
    int bc = g / 9, k = g % 9;
    int kr = k / 3, kc = k % 3;
    const float4* p4 = (const float4*)(x + (size_t)bc * HW);
    int row = kr * 32 + (l >> 1);
    int c0  = kc * 8 + (l & 1) * 4;
    const float4* pr = p4 + row * 24 + c0;
    float4 v0 = pr[0], v1 = pr[1], v2 = pr[2], v3 = pr[3];
    float s = (v0.x + v0.y + v0.z + v0.w) + (v1.x + v1.y + v1.z + v1.w)
            + (v2.x + v2.y + v2.z + v2.w) + (v3.x + v3.y + v3.z + v3.w);
    float m = fmaxf(fmaxf(fmaxf(v0.x, v0.y), fmaxf(v0.z, v0.w)),
             fmaxf(fmaxf(fmaxf(v1.x, v1.y), fmaxf(v1.z, v1.w)),
             fmaxf(fmaxf(fmaxf(v2.x, v2.y), fmaxf(v2.z, v2.w)),
                   fmaxf(fmaxf(v3.x, v3.y), fmaxf(v3.z, v3.w)))));
#pragma unroll
    for (int off = 32; off > 0; off >>= 1) {
        s += __shfl_down(s, off);
        m = fmaxf(m, __shfl_down(m, off));
    }
    if (l == 0) {
        pooled[g] = s * (1.0f / 1024.0f);
        wmax[g]   = m;
    }
}

// ---------------------------------------------------------------------------
// Kernel 2a: per-batch theta + h = relu(bn(proj1(pooled))).
// Finishes avg (= mean of 9 pooled) and mx (= max of 9 wmax) in LDS.
// ---------------------------------------------------------------------------
__global__ __launch_bounds__(256) void k_coeff1(
    const float* __restrict__ pooled, const float* __restrict__ wmax,
    const float* __restrict__ cam_w1, const float* __restrict__ cam_w2,
    const float* __restrict__ proj_w1,
    const float* __restrict__ bn_gamma, const float* __restrict__ bn_beta,
    float* __restrict__ theta, float* __restrict__ hh)
{
    int b = blockIdx.x;
    int t = threadIdx.x;
    __shared__ float s_av[CCH], s_mx[CCH], s_pool[CCH * 9], s_wm[CCH * 9];
    __shared__ float s_h1p[96], s_h1[RCH];
    for (int i = t; i < CCH * 9; i += 256) {
        s_pool[i] = pooled[b * CCH * 9 + i];
        s_wm[i]   = wmax[b * CCH * 9 + i];
    }
    __syncthreads();
    if (t < CCH) {
        float sa = 0.f, sm = -INFINITY;
#pragma unroll
        for (int k = 0; k < 9; ++k) {
            sa += s_pool[t * 9 + k];
            sm = fmaxf(sm, s_wm[t * 9 + k]);
        }
        s_av[t] = sa * (1.0f / 9.0f);
        s_mx[t] = sm;
    }
    __syncthreads();
    if (t < 96) {
        int r = t % 48, sel = t / 48;
        const float* src = sel ? s_mx : s_av;
        const float* w = cam_w1 + r * CCH;
        float acc = 0.f;
        for (int c = 0; c < CCH; ++c) acc += src[c] * w[c];
        s_h1p[sel * 48 + r] = fmaxf(acc, 0.f);
    }
    __syncthreads();
    if (t < RCH) s_h1[t] = s_h1p[t] + s_h1p[48 + t];
    __syncthreads();
    if (t < CCH) {
        const float* w = cam_w2 + t * RCH;
        float acc = 0.f;
        for (int r = 0; r < RCH; ++r) acc += s_h1[r] * w[r];
        theta[b * CCH + t] = 1.0f / (1.0f + expf(-acc));
    }
    float bn_s = 1.0f / sqrtf(1.0f + 1e-5f);
    for (int i = t; i < RCH * 9; i += 256) {
        int r = i / 9, k = i % 9;
        const float* w = proj_w1 + r * CCH;
        float acc = 0.f;
        for (int c = 0; c < CCH; ++c) acc += s_pool[c * 9 + k] * w[c];
        float val = acc * (bn_gamma[r] * bn_s) + bn_beta[r];
        hh[b * RCH * 9 + i] = fmaxf(val, 0.f);
    }
}

// ---------------------------------------------------------------------------
// Kernel 2b: per-(b,c,k) softmax over G=4 groups -> conv weight
// ---------------------------------------------------------------------------
__global__ __launch_bounds__(256) void k_coeff2(
    const float* __restrict__ hh, const float* __restrict__ proj_w2,
    const float* __restrict__ adk, float* __restrict__ wgt)
{
    int gid = blockIdx.x * 256 + threadIdx.x;
    if (gid >= BCTOT * 9) return;
    int b = gid / (CCH * 9);
    int rem = gid % (CCH * 9);
    int c = rem / 9, k = rem % 9;
    const float* hv = hh + b * RCH * 9 + k;
    float sg[4];
#pragma unroll
    for (int g = 0; g < 4; ++g) {
        const float* w = proj_w2 + (size_t)(g * CCH + c) * RCH;
        float acc = 0.f;
        for (int r = 0; r < RCH; ++r) acc += hv[r * 9] * w[r];
        sg[g] = acc;
    }
    float mxv = fmaxf(fmaxf(sg[0], sg[1]), fmaxf(sg[2], sg[3]));
    float e[4];
    float sum = 0.f;
#pragma unroll
    for (int g = 0; g < 4; ++g) { e[g] = expf(sg[g] - mxv); sum += e[g]; }
    float inv = 1.0f / sum;
    float acc = 0.f;
#pragma unroll
    for (int g = 0; g < 4; ++g)
        acc += (e[g] * inv) * adk[(size_t)(g * CCH + c) * 9 + k];
    wgt[gid] = acc;
}

// ---------------------------------------------------------------------------
// Kernel 3: depthwise 3x3 conv (pad 1), vertical sliding window (R2 mapping).
// Halo columns via __shfl_up/down(1): in the flat sub=rg*24+wq mapping,
// lane±1 == wq±1 within the same rowgroup; image edges (wq==0/23) are
// predicated to zero, and the two wave-edge lanes (l==0/63) fall back to a
// single-lane exec-masked scalar load. Eliminates the two 24-lane scattered
// scalar edge loads per row while keeping mapping/concurrency R2-exact.
// ---------------------------------------------------------------------------
__global__ __launch_bounds__(256) void k_conv(
    const float* __restrict__ x, const float* __restrict__ wgt,
    const float* __restrict__ theta, float* __restrict__ out)
{
    int gid = blockIdx.x * 256 + threadIdx.x;
    int plane = gid / 192;          // 192 = 8 rowgroups * 24 wq
    int sub   = gid % 192;
    int rg = sub / 24, wq = sub % 24;
    int l  = threadIdx.x & 63;
    int r0 = rg * 12;
    int w0 = wq * 4;

    float wr[9];
    float wsum = 0.f;
#pragma unroll
    for (int k = 0; k < 9; ++k) { wr[k] = wgt[plane * 9 + k]; wsum += wr[k]; }
    float th = theta[plane];
    wr[4] = wr[4] * (1.f + th) - wsum;   // fold theta-center adjustment

    const float* p = x + (size_t)plane * HW;
    const float4* p4 = (const float4*)p;
    float* o = out + (size_t)plane * HW;

    float acc[3][4];
#pragma unroll
    for (int i = 0; i <= 13; ++i) {
        int r = r0 - 1 + i;
        bool inr = (r >= 0) && (r < 96);
        float4 a;
        if (inr) a = p4[r * 24 + wq];
        else     a = make_float4(0.f, 0.f, 0.f, 0.f);

        float lhs = __shfl_up(a.w, 1);     // lane l-1 = same rg, wq-1 (when wq>0)
        float rhs = __shfl_down(a.x, 1);   // lane l+1 = same rg, wq+1 (when wq<23)
        float lh = (wq == 0)  ? 0.f : lhs;
        float rh = (wq == 23) ? 0.f : rhs;
        if (l == 0 && wq != 0)   lh = inr ? p[r * 96 + w0 - 1] : 0.f;
        if (l == 63 && wq != 23) rh = inr ? p[r * 96 + w0 + 4] : 0.f;

        float win[6];
        win[0] = lh;
        win[1] = a.x; win[2] = a.y; win[3] = a.z; win[4] = a.w;
        win[5] = rh;

        if (i <= 11) {
#pragma unroll
            for (int j = 0; j < 4; ++j)
                acc[i % 3][j] = wr[0] * win[j] + wr[1] * win[j + 1] + wr[2] * win[j + 2];
        }
        if (i >= 1 && i <= 12) {
#pragma unroll
            for (int j = 0; j < 4; ++j)
                acc[(i - 1) % 3][j] += wr[3] * win[j] + wr[4] * win[j + 1] + wr[5] * win[j + 2];
        }
        if (i >= 2) {
            const int s = (i - 2) % 3;
#pragma unroll
            for (int j = 0; j < 4; ++j)
                acc[s][j] += wr[6] * win[j] + wr[7] * win[j + 1] + wr[8] * win[j + 2];
            float4 o4;
            o4.x = acc[s][0]; o4.y = acc[s][1]; o4.z = acc[s][2]; o4.w = acc[s][3];
            ((float4*)(o + (size_t)(r - 1) * 96))[wq] = o4;
        }
    }
}

extern "C" void kernel_launch(void* const* d_in, const int* in_sizes, int n_in,
                              void* d_out, int out_size, void* d_ws, size_t ws_size,
                              hipStream_t stream) {
    const float* x        = (const float*)d_in[0];
    const float* cam_w1   = (const float*)d_in[1];
    const float* cam_w2   = (const float*)d_in[2];
    const float* proj_w1  = (const float*)d_in[3];
    const float* bn_gamma = (const float*)d_in[4];
    const float* bn_beta  = (const float*)d_in[5];
    const float* proj_w2  = (const float*)d_in[6];
    const float* adk      = (const float*)d_in[7];
    float* out = (float*)d_out;
    float* ws  = (float*)d_ws;

    float* pooled = ws;            // 27648
    float* wmaxg  = ws + 27648;    // 27648 (aliased: wgt after coeff1 consumes)
    float* theta  = ws + 55296;    // 3072
    float* hh     = ws + 58368;    // 6912
    float* wgt    = wmaxg;         // alias — wmax dead after k_coeff1

    k_stats  <<<(BCTOT * 9) / 4, 256, 0, stream>>>(x, pooled, wmaxg);   // 6912 blocks
    k_coeff1 <<<NB, 256, 0, stream>>>(pooled, wmaxg, cam_w1, cam_w2,
                                      proj_w1, bn_gamma, bn_beta, theta, hh);
    k_coeff2 <<<(BCTOT * 9) / 256, 256, 0, stream>>>(hh, proj_w2, adk, wgt);
    k_conv   <<<(BCTOT * 192) / 256, 256, 0, stream>>>(x, wgt, theta, out);
}